// Round 2
// baseline (497.317 us; speedup 1.0000x reference)
//
#include <hip/hip_runtime.h>
#include <hip/hip_bf16.h>

typedef __hip_bfloat16 bf16;
typedef __bf16 bf16x8 __attribute__((ext_vector_type(8)));
typedef float f32x4 __attribute__((ext_vector_type(4)));

#define NEG_SLOPE 0.2f
#define F32_THRESH 256

// ---------------- dtype helpers ---------------------------------------------

__device__ __forceinline__ bool is_f32(const int* fcnt) { return *fcnt > F32_THRESH; }

__device__ __forceinline__ float ld_f(const void* p, long long i, bool f32) {
    return f32 ? ((const float*)p)[i] : __bfloat162float(((const bf16*)p)[i]);
}

// Count bf16 NaN/Inf bit patterns in low halves of 32-bit words.
// bf16 data -> 0 hits. fp32 data -> ~0.4% of words hit.
__global__ void k_sniff(const unsigned* w, long long nw, int* cnt) {
    int c = 0;
    for (long long i = blockIdx.x * (long long)blockDim.x + threadIdx.x; i < nw;
         i += (long long)gridDim.x * blockDim.x)
        if ((w[i] & 0x7F80u) == 0x7F80u) c++;
    if (c) atomicAdd(cnt, c);
}

__global__ void k_tobf16(const void* src, const int* fcnt, bf16* dst, long long n) {
    bool f32 = is_f32(fcnt);
    for (long long i = blockIdx.x * (long long)blockDim.x + threadIdx.x; i < n;
         i += (long long)gridDim.x * blockDim.x)
        dst[i] = __float2bfloat16(ld_f(src, i, f32));
}

// ---------------- edge index (int32 vs int64 runtime detect) ----------------

__global__ void k_detect_i32(const int* idx, int n_half, int* iflag) {
    // int64 (LE) data: odd words are high halves == 0. int32: odd words are
    // real node indices, essentially never all zero.
    int any = 0;
    for (int i = blockIdx.x * blockDim.x + threadIdx.x; i < n_half;
         i += gridDim.x * blockDim.x)
        if (idx[2 * i + 1] != 0) any = 1;
    if (any) atomicOr(iflag, 1);
}

__device__ __forceinline__ int edge_val(const void* idx, long long i, int is64) {
    return is64 ? (int)((const long long*)idx)[i] : ((const int*)idx)[i];
}

// ---------------- CSR build (hardened: all indices clamped) -----------------

__global__ void k_count(const void* idx, const int* iflag, int E0, int N, int* deg) {
    int e = blockIdx.x * blockDim.x + threadIdx.x;
    if (e >= E0 + N) return;
    int is64 = (*iflag == 0);
    int d = (e < E0) ? edge_val(idx, (long long)E0 + e, is64) : (e - E0);
    if ((unsigned)d >= (unsigned)N) d = 0;
    atomicAdd(&deg[d], 1);
}

__global__ __launch_bounds__(1024) void k_scan(const int* deg, int* rowptr, int N) {
    __shared__ int part[1024];
    int t = threadIdx.x;
    int chunk = (N + 1023) / 1024;
    int s = t * chunk, e = min(N, s + chunk);
    int sum = 0;
    for (int i = s; i < e; i++) sum += deg[i];
    part[t] = sum;
    __syncthreads();
    for (int off = 1; off < 1024; off <<= 1) {
        int v = (t >= off) ? part[t - off] : 0;
        __syncthreads();
        part[t] += v;
        __syncthreads();
    }
    int run = (t == 0) ? 0 : part[t - 1];
    for (int i = s; i < e; i++) { rowptr[i] = run; run += deg[i]; }
    if (t == 1023) rowptr[N] = part[1023];
}

__global__ void k_scatter(const void* idx, const int* iflag, int E0, int N,
                          const int* rowptr, int* cursor, int* csr_src) {
    int e = blockIdx.x * blockDim.x + threadIdx.x;
    if (e >= E0 + N) return;
    int is64 = (*iflag == 0);
    int s, d;
    if (e < E0) {
        s = edge_val(idx, e, is64);
        d = edge_val(idx, (long long)E0 + e, is64);
    } else {
        s = d = e - E0;
    }
    if ((unsigned)s >= (unsigned)N) s = 0;
    if ((unsigned)d >= (unsigned)N) d = 0;
    int pos = rowptr[d] + atomicAdd(&cursor[d], 1);
    if ((unsigned)pos < (unsigned)(E0 + N)) csr_src[pos] = s;
}

// ---------------- weight transpose (dtype-aware) ----------------------------

__global__ void k_transpose(const void* W, const int* fcnt, bf16* Wt, int K, int N) {
    int i = blockIdx.x * blockDim.x + threadIdx.x;
    if (i >= K * N) return;
    bool f32 = is_f32(fcnt);
    int k = i / N, n = i % N;
    Wt[(size_t)n * K + k] = __float2bfloat16(ld_f(W, i, f32));
}

// ---------------- attention logits ------------------------------------------

__global__ void k_al(const bf16* h, const void* a_s, const void* a_d, const int* fcnt,
                     float* als, float* ald, int N, int H, int Ch) {
    int i = blockIdx.x * blockDim.x + threadIdx.x;
    if (i >= N * H) return;
    bool f32 = is_f32(fcnt);
    int n = i / H, hh = i % H;
    const bf16* row = h + (size_t)n * H * Ch + hh * Ch;
    float s = 0.f, d = 0.f;
    for (int c = 0; c < Ch; c++) {
        float v = __bfloat162float(row[c]);
        s += v * ld_f(a_s, hh * Ch + c, f32);
        d += v * ld_f(a_d, hh * Ch + c, f32);
    }
    als[i] = s;
    ald[i] = d;
}

// ---------------- MFMA GEMM: C[M,N] = A[M,K] @ Bt[N,K]^T, bf16 --------------

__global__ __launch_bounds__(256) void k_gemm(const bf16* A, const bf16* Bt,
                                              bf16* C, int M, int Nn, int K) {
    const int m0 = blockIdx.x * 64;
    const int n0 = blockIdx.y * 64;
    __shared__ __bf16 As[64][32];
    __shared__ __bf16 Bs[64][32];
    const int tid = threadIdx.x;
    const int wave = tid >> 6;
    const int lane = tid & 63;
    const int lm = lane & 15;
    const int quad = lane >> 4;
    const int lr = tid >> 2;  // staging row 0..63
    const int lq = tid & 3;   // staging 16B chunk 0..3

    f32x4 acc[4];
#pragma unroll
    for (int nt = 0; nt < 4; nt++) acc[nt] = (f32x4){0.f, 0.f, 0.f, 0.f};

    for (int k0 = 0; k0 < K; k0 += 32) {
        __syncthreads();
        uint4 av = make_uint4(0, 0, 0, 0);
        if (m0 + lr < M)
            av = *(const uint4*)(A + (size_t)(m0 + lr) * K + k0 + lq * 8);
        *(uint4*)(&As[lr][lq * 8]) = av;
        uint4 bv = *(const uint4*)(Bt + (size_t)(n0 + lr) * K + k0 + lq * 8);
        *(uint4*)(&Bs[lr][lq * 8]) = bv;
        __syncthreads();
        bf16x8 af = *(const bf16x8*)(&As[wave * 16 + lm][quad * 8]);
#pragma unroll
        for (int nt = 0; nt < 4; nt++) {
            bf16x8 bfv = *(const bf16x8*)(&Bs[nt * 16 + lm][quad * 8]);
            acc[nt] = __builtin_amdgcn_mfma_f32_16x16x32_bf16(af, bfv, acc[nt], 0, 0, 0);
        }
    }
#pragma unroll
    for (int nt = 0; nt < 4; nt++) {
#pragma unroll
        for (int r = 0; r < 4; r++) {
            int row = m0 + wave * 16 + quad * 4 + r;
            int col = n0 + nt * 16 + lm;
            if (row < M) C[(size_t)row * Nn + col] = __float2bfloat16(acc[nt][r]);
        }
    }
}

// ---------------- per-dst softmax aggregation (hardened) --------------------
template <int C, int H, int NPT, bool ELU, bool DYN_OUT>
__global__ __launch_bounds__(C / NPT) void k_agg(
    const bf16* feat, const float* als, const float* ald, const int* rowptr,
    const int* csr_src, const void* bias, const int* fcnt, void* outp,
    int N, int E) {
    constexpr int BS = C / NPT;
    constexpr int Ch = C / H;
    const int n = blockIdx.x;
    const int tid = threadIdx.x;
    const int c0 = tid * NPT;
    const int head = c0 / Ch;
    const bool f32 = is_f32(fcnt);

    __shared__ float s_max[H];
    __shared__ float s_sum[H];
    __shared__ float s_w[64][H];
    __shared__ int s_src[64];
    __shared__ float red[BS];

    int start = rowptr[n];
    if (start < 0) start = 0;
    int end = rowptr[n + 1];
    if (end > E) end = E;
    int deg = end - start;
    if (deg < 0) deg = 0;

    float aldn[H];
#pragma unroll
    for (int h = 0; h < H; h++) aldn[h] = ald[(size_t)n * H + h];

    // phase 1: per-head max over incoming edges (all threads stride)
    float mx[H];
#pragma unroll
    for (int h = 0; h < H; h++) mx[h] = -1e30f;
    for (int e = tid; e < deg; e += BS) {
        int s = csr_src[start + e];
        if ((unsigned)s >= (unsigned)N) s = 0;
#pragma unroll
        for (int h = 0; h < H; h++) {
            float l = als[(size_t)s * H + h] + aldn[h];
            l = l > 0.f ? l : NEG_SLOPE * l;
            mx[h] = fmaxf(mx[h], l);
        }
    }
#pragma unroll
    for (int h = 0; h < H; h++) {
        red[tid] = mx[h];
        __syncthreads();
        for (int st = BS / 2; st > 0; st >>= 1) {
            if (tid < st) red[tid] = fmaxf(red[tid], red[tid + st]);
            __syncthreads();
        }
        if (tid == 0) s_max[h] = red[0];
        __syncthreads();
    }

    // phase 2: weights + weighted feature accumulation
    float acc[NPT];
#pragma unroll
    for (int p = 0; p < NPT; p++) acc[p] = 0.f;
    float psum[H];
#pragma unroll
    for (int h = 0; h < H; h++) psum[h] = 0.f;

    for (int base = 0; base < deg; base += 64) {
        int cnt = min(64, deg - base);
        __syncthreads();
        if (tid < cnt) {
            int s = csr_src[start + base + tid];
            if ((unsigned)s >= (unsigned)N) s = 0;
            s_src[tid] = s;
#pragma unroll
            for (int h = 0; h < H; h++) {
                float l = als[(size_t)s * H + h] + aldn[h];
                l = l > 0.f ? l : NEG_SLOPE * l;
                float w = expf(fminf(l - s_max[h], 0.f));  // clamp: no inf possible
                s_w[tid][h] = w;
                psum[h] += w;
            }
        }
        __syncthreads();
        for (int e = 0; e < cnt; e++) {
            int s = s_src[e];
            float w = s_w[e][head];
            const bf16* fr = feat + (size_t)s * C + c0;
            if (NPT == 2) {
                union { unsigned u; unsigned short h2[2]; } u2;
                u2.u = *(const unsigned*)fr;
                union { unsigned short us; __hip_bfloat16_raw r; } c0u{u2.h2[0]}, c1u{u2.h2[1]};
                acc[0] += w * __bfloat162float((bf16)c0u.r);
                acc[1] += w * __bfloat162float((bf16)c1u.r);
            } else {
                acc[0] += w * __bfloat162float(fr[0]);
            }
        }
    }

    // denominators
#pragma unroll
    for (int h = 0; h < H; h++) {
        red[tid] = psum[h];
        __syncthreads();
        for (int st = BS / 2; st > 0; st >>= 1) {
            if (tid < st) red[tid] += red[tid + st];
            __syncthreads();
        }
        if (tid == 0) s_sum[h] = red[0];
        __syncthreads();
    }

    float denom = s_sum[head] + 1e-16f;
#pragma unroll
    for (int p = 0; p < NPT; p++) {
        float v = acc[p] / denom + ld_f(bias, c0 + p, f32);
        if (ELU) v = v > 0.f ? v : expf(v) - 1.f;
        size_t oi = (size_t)n * C + c0 + p;
        if (DYN_OUT && f32) ((float*)outp)[oi] = v;
        else ((bf16*)outp)[oi] = __float2bfloat16(v);
    }
}

// ---------------- launch -----------------------------------------------------

extern "C" void kernel_launch(void* const* d_in, const int* in_sizes, int n_in,
                              void* d_out, int out_size, void* d_ws, size_t ws_size,
                              hipStream_t stream) {
    const int N = in_sizes[0] / 512;  // 20000
    const int K = 512;                // IN_C
    const int C1 = 512;               // HEADS*OUT_C
    const int C2 = 128;               // OUT_C
    const int H1 = 4;
    const int E0 = in_sizes[1] / 2;   // 320000
    const int E = E0 + N;

    const void* x_raw = d_in[0];
    const void* eidx = d_in[1];
    const void* W1 = d_in[2];
    const void* as1 = d_in[3];
    const void* ad1 = d_in[4];
    const void* b1 = d_in[5];
    const void* W2 = d_in[6];
    const void* as2 = d_in[7];
    const void* ad2 = d_in[8];
    const void* b2 = d_in[9];

    char* ws = (char*)d_ws;
    size_t off = 0;
    auto take = [&](size_t bytes) {
        size_t r = off;
        off += (bytes + 255) & ~(size_t)255;
        return r;
    };
    bf16* xb     = (bf16*)(ws + take((size_t)N * K * 2));
    bf16* h1     = (bf16*)(ws + take((size_t)N * C1 * 2));
    bf16* hagg   = (bf16*)(ws + take((size_t)N * C1 * 2));
    bf16* h2     = (bf16*)(ws + take((size_t)N * C2 * 2));
    bf16* W1t    = (bf16*)(ws + take((size_t)K * C1 * 2));
    bf16* W2t    = (bf16*)(ws + take((size_t)C1 * C2 * 2));
    float* al1s  = (float*)(ws + take((size_t)N * H1 * 4));
    float* al1d  = (float*)(ws + take((size_t)N * H1 * 4));
    float* al2s  = (float*)(ws + take((size_t)N * 4));
    float* al2d  = (float*)(ws + take((size_t)N * 4));
    int* rowptr  = (int*)(ws + take((size_t)(N + 1) * 4));
    int* csr_src = (int*)(ws + take((size_t)E * 4));
    // contiguous zero-init region: deg, cursor, iflag, fcnt
    int* deg     = (int*)(ws + take((size_t)(2 * N + 2) * 4));
    int* cursor  = deg + N;
    int* iflag   = deg + 2 * N;
    int* fcnt    = deg + 2 * N + 1;
    if (off > ws_size) return;  // visible failure: out stays zero

    hipMemsetAsync(deg, 0, (size_t)(2 * N + 2) * 4, stream);
    hipMemsetAsync(csr_src, 0, (size_t)E * 4, stream);

    // dtype sniffs
    k_sniff<<<1024, 256, 0, stream>>>((const unsigned*)x_raw, (long long)in_sizes[0] / 2, fcnt);
    k_detect_i32<<<256, 256, 0, stream>>>((const int*)eidx, E0, iflag);

    // CSR build
    k_count<<<(E + 255) / 256, 256, 0, stream>>>(eidx, iflag, E0, N, deg);
    k_scan<<<1, 1024, 0, stream>>>(deg, rowptr, N);
    k_scatter<<<(E + 255) / 256, 256, 0, stream>>>(eidx, iflag, E0, N, rowptr, cursor, csr_src);

    // normalize inputs to bf16
    k_tobf16<<<2048, 256, 0, stream>>>(x_raw, fcnt, xb, (long long)N * K);
    k_transpose<<<(K * C1 + 255) / 256, 256, 0, stream>>>(W1, fcnt, W1t, K, C1);
    k_transpose<<<(C1 * C2 + 255) / 256, 256, 0, stream>>>(W2, fcnt, W2t, C1, C2);

    // layer 1
    dim3 g1((N + 63) / 64, C1 / 64);
    k_gemm<<<g1, 256, 0, stream>>>(xb, W1t, h1, N, C1, K);
    k_al<<<(N * H1 + 255) / 256, 256, 0, stream>>>(h1, as1, ad1, fcnt, al1s, al1d, N, H1, 128);
    k_agg<512, 4, 2, true, false><<<N, 256, 0, stream>>>(h1, al1s, al1d, rowptr, csr_src,
                                                         b1, fcnt, hagg, N, E);

    // layer 2
    dim3 g2((N + 63) / 64, C2 / 64);
    k_gemm<<<g2, 256, 0, stream>>>(hagg, W2t, h2, N, C2, C1);
    k_al<<<(N + 255) / 256, 256, 0, stream>>>(h2, as2, ad2, fcnt, al2s, al2d, N, 1, 128);
    k_agg<128, 1, 1, false, true><<<N, 128, 0, stream>>>(h2, al2s, al2d, rowptr, csr_src,
                                                         b2, fcnt, d_out, N, E);
}

// Round 3
// 320.636 us; speedup vs baseline: 1.5510x; 1.5510x over previous
//
#include <hip/hip_runtime.h>
#include <hip/hip_bf16.h>

typedef __hip_bfloat16 bf16;
typedef __bf16 bf16x8 __attribute__((ext_vector_type(8)));
typedef float f32x4 __attribute__((ext_vector_type(4)));

#define NEG_SLOPE 0.2f
#define F32_THRESH 256

// ---------------- helpers ----------------------------------------------------

__device__ __forceinline__ bool is_f32(const int* fcnt) { return *fcnt > F32_THRESH; }

__device__ __forceinline__ float ld_f(const void* p, long long i, bool f32) {
    return f32 ? ((const float*)p)[i] : __bfloat162float(((const bf16*)p)[i]);
}

__device__ __forceinline__ float b2f(unsigned hs) {
    return __uint_as_float(hs << 16);
}

__device__ __forceinline__ void load_lds16(const void* g, void* l) {
    __builtin_amdgcn_global_load_lds(
        (const __attribute__((address_space(1))) void*)g,
        (__attribute__((address_space(3))) void*)l, 16, 0, 0);
}

// Count bf16 NaN/Inf patterns in low halves of words: bf16 data -> 0,
// fp32 data -> ~0.4% of words.
__global__ void k_sniff(const unsigned* w, long long nw, int* cnt) {
    int c = 0;
    for (long long i = blockIdx.x * (long long)blockDim.x + threadIdx.x; i < nw;
         i += (long long)gridDim.x * blockDim.x)
        if ((w[i] & 0x7F80u) == 0x7F80u) c++;
    if (c) atomicAdd(cnt, c);
}

// n_valid elements converted; [n_valid, n_total) zero-filled (pad rows).
__global__ void k_tobf16(const void* src, const int* fcnt, bf16* dst,
                         long long n_valid, long long n_total) {
    bool f32 = is_f32(fcnt);
    for (long long i = blockIdx.x * (long long)blockDim.x + threadIdx.x; i < n_total;
         i += (long long)gridDim.x * blockDim.x)
        dst[i] = (i < n_valid) ? __float2bfloat16(ld_f(src, i, f32))
                               : __float2bfloat16(0.f);
}

// ---------------- edge index (int32 vs int64 runtime detect) ----------------

__global__ void k_detect_i32(const int* idx, int n_half, int* iflag) {
    int any = 0;
    for (int i = blockIdx.x * blockDim.x + threadIdx.x; i < n_half;
         i += gridDim.x * blockDim.x)
        if (idx[2 * i + 1] != 0) any = 1;
    if (any) atomicOr(iflag, 1);
}

__device__ __forceinline__ int edge_val(const void* idx, long long i, int is64) {
    return is64 ? (int)((const long long*)idx)[i] : ((const int*)idx)[i];
}

// ---------------- CSR build (hardened) --------------------------------------

__global__ void k_count(const void* idx, const int* iflag, int E0, int N, int* deg) {
    int e = blockIdx.x * blockDim.x + threadIdx.x;
    if (e >= E0 + N) return;
    int is64 = (*iflag == 0);
    int d = (e < E0) ? edge_val(idx, (long long)E0 + e, is64) : (e - E0);
    if ((unsigned)d >= (unsigned)N) d = 0;
    atomicAdd(&deg[d], 1);
}

__global__ __launch_bounds__(1024) void k_scan(const int* deg, int* rowptr, int N) {
    __shared__ int part[1024];
    int t = threadIdx.x;
    int chunk = (N + 1023) / 1024;
    int s = t * chunk, e = min(N, s + chunk);
    int sum = 0;
    for (int i = s; i < e; i++) sum += deg[i];
    part[t] = sum;
    __syncthreads();
    for (int off = 1; off < 1024; off <<= 1) {
        int v = (t >= off) ? part[t - off] : 0;
        __syncthreads();
        part[t] += v;
        __syncthreads();
    }
    int run = (t == 0) ? 0 : part[t - 1];
    for (int i = s; i < e; i++) { rowptr[i] = run; run += deg[i]; }
    if (t == 1023) rowptr[N] = part[1023];
}

__global__ void k_scatter(const void* idx, const int* iflag, int E0, int N,
                          const int* rowptr, int* cursor, int* csr_src) {
    int e = blockIdx.x * blockDim.x + threadIdx.x;
    if (e >= E0 + N) return;
    int is64 = (*iflag == 0);
    int s, d;
    if (e < E0) {
        s = edge_val(idx, e, is64);
        d = edge_val(idx, (long long)E0 + e, is64);
    } else {
        s = d = e - E0;
    }
    if ((unsigned)s >= (unsigned)N) s = 0;
    if ((unsigned)d >= (unsigned)N) d = 0;
    int pos = rowptr[d] + atomicAdd(&cursor[d], 1);
    if ((unsigned)pos < (unsigned)(E0 + N)) csr_src[pos] = s;
}

// ---------------- weight transpose ------------------------------------------

__global__ void k_transpose(const void* W, const int* fcnt, bf16* Wt, int K, int N) {
    int i = blockIdx.x * blockDim.x + threadIdx.x;
    if (i >= K * N) return;
    bool f32 = is_f32(fcnt);
    int k = i / N, n = i % N;
    Wt[(size_t)n * K + k] = __float2bfloat16(ld_f(W, i, f32));
}

// ---------------- attention logits (vectorized) -----------------------------

__global__ void k_al(const bf16* __restrict__ h, const void* a_s, const void* a_d,
                     const int* fcnt, float* als, float* ald, int N, int H) {
    __shared__ float sa[512], sd[512];
    const int HC = H * 128;
    bool f32 = is_f32(fcnt);
    for (int i = threadIdx.x; i < HC; i += blockDim.x) {
        sa[i] = ld_f(a_s, i, f32);
        sd[i] = ld_f(a_d, i, f32);
    }
    __syncthreads();
    int i = blockIdx.x * blockDim.x + threadIdx.x;
    if (i >= N * H) return;
    int n = i / H, hh = i % H;
    const uint4* row = (const uint4*)(h + (size_t)n * HC + hh * 128);
    float s = 0.f, d = 0.f;
#pragma unroll
    for (int q = 0; q < 16; q++) {
        uint4 u = row[q];
        unsigned uu[4] = {u.x, u.y, u.z, u.w};
#pragma unroll
        for (int t = 0; t < 4; t++) {
            float v0 = b2f(uu[t] & 0xFFFFu), v1 = b2f(uu[t] >> 16);
            int c = hh * 128 + q * 8 + t * 2;
            s += v0 * sa[c] + v1 * sa[c + 1];
            d += v0 * sd[c] + v1 * sd[c + 1];
        }
    }
    als[i] = s;
    ald[i] = d;
}

// ---------------- MFMA GEMM (m97-style): C[M,Nn] = A @ Bt^T -----------------
// BM=128, BK=32, BN template (128 or 64). A padded to 128-row multiple.

template <int BN>
__global__ __launch_bounds__(256) void k_gemm(const bf16* __restrict__ A,
                                              const bf16* __restrict__ Bt,
                                              bf16* __restrict__ C,
                                              int M, int Nn, int K) {
    constexpr int BM = 128, BK = 32;
    constexpr int NT = BN / 32;  // 16-wide n-tiles per wave
    const int m0 = blockIdx.x * BM;
    const int n0 = blockIdx.y * BN;
    __shared__ __bf16 As[BM][BK];
    __shared__ __bf16 Bs[BN][BK];
    const int tid = threadIdx.x;
    const int wave = tid >> 6;
    const int lane = tid & 63;
    const int wm = (wave & 1) * 64;
    const int wn = (wave >> 1) * (NT * 16);
    const int lm = lane & 15;
    const int quad = lane >> 4;
    const int srow = tid >> 2;         // staging row 0..63
    const int scol = (tid & 3) * 8;    // staging col (elements)

    f32x4 acc[4][NT];
#pragma unroll
    for (int mt = 0; mt < 4; mt++)
#pragma unroll
        for (int nt = 0; nt < NT; nt++) acc[mt][nt] = (f32x4){0.f, 0.f, 0.f, 0.f};

    const char* Ab = (const char*)(A + (size_t)(m0 + srow) * K + scol);
    const char* Bb = (const char*)(Bt + (size_t)(n0 + srow) * K + scol);
    char* ldsA = (char*)&As[0][0] + wave * 1024;
    char* ldsB = (char*)&Bs[0][0] + wave * 1024;
    const size_t rstep = (size_t)64 * K * 2;  // +64 rows in bytes

    for (int k0 = 0; k0 < K; k0 += BK) {
        __syncthreads();
        const size_t kb = (size_t)k0 * 2;
        load_lds16(Ab + kb, ldsA);
        load_lds16(Ab + kb + rstep, ldsA + 4096);
        load_lds16(Bb + kb, ldsB);
        if (BN == 128) load_lds16(Bb + kb + rstep, ldsB + 4096);
        __syncthreads();
        bf16x8 af[4], bfv[NT];
#pragma unroll
        for (int mt = 0; mt < 4; mt++)
            af[mt] = *(const bf16x8*)&As[wm + mt * 16 + lm][quad * 8];
#pragma unroll
        for (int nt = 0; nt < NT; nt++)
            bfv[nt] = *(const bf16x8*)&Bs[wn + nt * 16 + lm][quad * 8];
#pragma unroll
        for (int mt = 0; mt < 4; mt++)
#pragma unroll
            for (int nt = 0; nt < NT; nt++)
                acc[mt][nt] = __builtin_amdgcn_mfma_f32_16x16x32_bf16(
                    af[mt], bfv[nt], acc[mt][nt], 0, 0, 0);
    }

#pragma unroll
    for (int mt = 0; mt < 4; mt++) {
        int rb = m0 + wm + mt * 16 + quad * 4;
#pragma unroll
        for (int nt = 0; nt < NT; nt++) {
            int col = n0 + wn + nt * 16 + lm;
#pragma unroll
            for (int r = 0; r < 4; r++) {
                int row = rb + r;
                if (row < M) C[(size_t)row * Nn + col] = __float2bfloat16(acc[mt][nt][r]);
            }
        }
    }
}

// ---------------- per-dst softmax aggregation (barrier-free) ----------------
// Wave-per-edge; lane owns C/64 channels; exp without max-shift (|logit|<~10,
// clamped at 60 for structural safety); single cross-wave LDS reduction.

template <int C, int H, bool ELU, bool DYN_OUT, int BS>
__global__ __launch_bounds__(BS) void k_agg(
    const bf16* __restrict__ feat, const float* __restrict__ als,
    const float* __restrict__ ald, const int* __restrict__ rowptr,
    const int* __restrict__ csr_src, const void* bias, const int* fcnt,
    void* outp, int N, int E) {
    constexpr int NW = BS / 64;
    constexpr int CPL = C / 64;
    constexpr int Ch = C / H;
    constexpr int OPT = C / BS;
    const int n = blockIdx.x;
    const int tid = threadIdx.x;
    const int wave = tid >> 6;
    const int lane = tid & 63;
    const int c0 = lane * CPL;
    const int head = c0 / Ch;

    __shared__ float red[NW][C];
    __shared__ float ps[NW][H];

    int start = rowptr[n];
    if (start < 0) start = 0;
    int end = rowptr[n + 1];
    if (end > E) end = E;
    int deg = end - start;
    if (deg < 0) deg = 0;

    float aldn[H];
#pragma unroll
    for (int h = 0; h < H; h++) aldn[h] = ald[(size_t)n * H + h];

    float acc[CPL] = {};
    float psum[H] = {};

#pragma unroll 2
    for (int e = wave; e < deg; e += NW) {
        int s = csr_src[start + e];
        if ((unsigned)s >= (unsigned)N) s = 0;
        float w[H];
        if (H == 4) {
            float4 av = ((const float4*)als)[s];
            float a4[4] = {av.x, av.y, av.z, av.w};
#pragma unroll
            for (int h = 0; h < 4; h++) {
                float l = a4[h] + aldn[h];
                l = l > 0.f ? l : NEG_SLOPE * l;
                w[h] = __expf(fminf(l, 60.f));
                psum[h] += w[h];
            }
        } else {
            float l = als[s] + aldn[0];
            l = l > 0.f ? l : NEG_SLOPE * l;
            w[0] = __expf(fminf(l, 60.f));
            psum[0] += w[0];
        }
        float wl;
        if (H == 1) wl = w[0];
        else wl = head < 2 ? (head == 0 ? w[0] : w[1]) : (head == 2 ? w[2] : w[3]);

        const bf16* fr = feat + (size_t)s * C + c0;
        if (CPL == 8) {
            uint4 u = *(const uint4*)fr;
            unsigned uu[4] = {u.x, u.y, u.z, u.w};
#pragma unroll
            for (int q = 0; q < 4; q++) {
                acc[2 * q] += wl * b2f(uu[q] & 0xFFFFu);
                acc[2 * q + 1] += wl * b2f(uu[q] >> 16);
            }
        } else {
            unsigned u = *(const unsigned*)fr;
            acc[0] += wl * b2f(u & 0xFFFFu);
            acc[1] += wl * b2f(u >> 16);
        }
    }

#pragma unroll
    for (int j = 0; j < CPL; j++) red[wave][c0 + j] = acc[j];
    if (lane == 0)
#pragma unroll
        for (int h = 0; h < H; h++) ps[wave][h] = psum[h];
    __syncthreads();

    const bool f32 = is_f32(fcnt);
#pragma unroll
    for (int p = 0; p < OPT; p++) {
        int c = tid * OPT + p;
        int h = c / Ch;
        float sv = 0.f;
#pragma unroll
        for (int w2 = 0; w2 < NW; w2++) sv += red[w2][c];
        float dn = 1e-16f;
#pragma unroll
        for (int w2 = 0; w2 < NW; w2++) dn += ps[w2][h];
        float v = sv / dn + ld_f(bias, c, f32);
        if (ELU) v = v > 0.f ? v : expf(v) - 1.f;
        size_t oi = (size_t)n * C + c;
        if (DYN_OUT && f32) ((float*)outp)[oi] = v;
        else ((bf16*)outp)[oi] = __float2bfloat16(v);
    }
}

// ---------------- launch -----------------------------------------------------

extern "C" void kernel_launch(void* const* d_in, const int* in_sizes, int n_in,
                              void* d_out, int out_size, void* d_ws, size_t ws_size,
                              hipStream_t stream) {
    const int N = in_sizes[0] / 512;  // 20000
    const int K = 512;
    const int C1 = 512;
    const int C2 = 128;
    const int H1 = 4;
    const int E0 = in_sizes[1] / 2;   // 320000
    const int E = E0 + N;
    const int Mpad = (N + 127) / 128 * 128;  // 20096

    const void* x_raw = d_in[0];
    const void* eidx = d_in[1];
    const void* W1 = d_in[2];
    const void* as1 = d_in[3];
    const void* ad1 = d_in[4];
    const void* b1 = d_in[5];
    const void* W2 = d_in[6];
    const void* as2 = d_in[7];
    const void* ad2 = d_in[8];
    const void* b2 = d_in[9];

    char* ws = (char*)d_ws;
    size_t off = 0;
    auto take = [&](size_t bytes) {
        size_t r = off;
        off += (bytes + 255) & ~(size_t)255;
        return r;
    };
    bf16* xb     = (bf16*)(ws + take((size_t)Mpad * K * 2));  // also reused for h2
    bf16* h1     = (bf16*)(ws + take((size_t)N * C1 * 2));
    bf16* hagg   = (bf16*)(ws + take((size_t)Mpad * C1 * 2));
    bf16* W1t    = (bf16*)(ws + take((size_t)K * C1 * 2));
    bf16* W2t    = (bf16*)(ws + take((size_t)C1 * C2 * 2));
    float* al1s  = (float*)(ws + take((size_t)N * H1 * 4));
    float* al1d  = (float*)(ws + take((size_t)N * H1 * 4));
    int* rowptr  = (int*)(ws + take((size_t)(N + 1) * 4));
    int* csr_src = (int*)(ws + take((size_t)E * 4));
    int* deg     = (int*)(ws + take((size_t)(2 * N + 2) * 4));
    int* cursor  = deg + N;
    int* iflag   = deg + 2 * N;
    int* fcnt    = deg + 2 * N + 1;
    bf16* h2     = xb;                 // alias: xb dead after gemm1
    float* al2s  = al1s;               // alias: al1 dead after agg1
    float* al2d  = al1d;
    if (off > ws_size) return;

    hipMemsetAsync(deg, 0, (size_t)(2 * N + 2) * 4, stream);
    hipMemsetAsync(csr_src, 0, (size_t)E * 4, stream);

    // dtype sniffs (capped scans)
    long long nw = (long long)in_sizes[0] / 2;
    if (nw > (1 << 20)) nw = 1 << 20;
    k_sniff<<<256, 256, 0, stream>>>((const unsigned*)x_raw, nw, fcnt);
    int nh = E0 > (1 << 16) ? (1 << 16) : E0;
    k_detect_i32<<<64, 256, 0, stream>>>((const int*)eidx, nh, iflag);

    // CSR build
    k_count<<<(E + 255) / 256, 256, 0, stream>>>(eidx, iflag, E0, N, deg);
    k_scan<<<1, 1024, 0, stream>>>(deg, rowptr, N);
    k_scatter<<<(E + 255) / 256, 256, 0, stream>>>(eidx, iflag, E0, N, rowptr, cursor, csr_src);

    // normalize inputs to bf16 (x padded+zero-filled to Mpad rows)
    k_tobf16<<<2048, 256, 0, stream>>>(x_raw, fcnt, xb, (long long)N * K, (long long)Mpad * K);
    k_transpose<<<(K * C1 + 255) / 256, 256, 0, stream>>>(W1, fcnt, W1t, K, C1);
    k_transpose<<<(C1 * C2 + 255) / 256, 256, 0, stream>>>(W2, fcnt, W2t, C1, C2);

    // layer 1
    dim3 g1(Mpad / 128, C1 / 128);
    k_gemm<128><<<g1, 256, 0, stream>>>(xb, W1t, h1, N, C1, K);
    k_al<<<(N * H1 + 255) / 256, 256, 0, stream>>>(h1, as1, ad1, fcnt, al1s, al1d, N, H1);
    k_agg<512, 4, true, false, 256><<<N, 256, 0, stream>>>(h1, al1s, al1d, rowptr, csr_src,
                                                           b1, fcnt, hagg, N, E);
    // zero hagg pad rows (gemm2 reads them; keep them clean)
    hipMemsetAsync(hagg + (size_t)N * C1, 0, (size_t)(Mpad - N) * C1 * 2, stream);

    // layer 2
    dim3 g2(Mpad / 128, C2 / 64);
    k_gemm<64><<<g2, 256, 0, stream>>>(hagg, W2t, h2, N, C2, C1);
    k_al<<<(N + 255) / 256, 256, 0, stream>>>(h2, as2, ad2, fcnt, al2s, al2d, N, 1);
    k_agg<128, 1, false, true, 128><<<N, 128, 0, stream>>>(h2, al2s, al2d, rowptr, csr_src,
                                                           b2, fcnt, d_out, N, E);
}